// Round 1
// 59.795 us; speedup vs baseline: 1.0248x; 1.0248x over previous
//
#include <hip/hip_runtime.h>
#include <math.h>

// Until_15753940041804: soft "until" operator.
// best[b,t,c] = log( sum_{k=0..63} 1/(S_k + exp(-s*psi[b,t+k,c])) ) / s
//   S_0 = exp(-s*1.0),  S_k = sum_{j<k} exp(-s*phi[b,t+j,c])  (k>=1).
// Padding: past T we stage ep=0 (phi pad +1e4) and eq=+inf (psi pad -1e4),
// reproducing the reference's pad + 'valid' mask exactly (rcp(inf)=0).
//
// R3 change vs R2: the 63-deep full unroll is replaced by an 8x8 chunked,
// explicitly double-buffered unroll. R2's full unroll let the scheduler
// hoist dozens of ds_read_b128 results -> VGPR exhaustion -> scratch spills
// (theory for the ~20us kernel vs ~4-5us issue/LDS floor). Now only
// buf[8]+nxt[8] (64 VGPRs) are live: 8 LDS loads in flight per chunk
// (~96 cyc LDS pipe) hidden under ~220 cyc of rcp/add compute, bounded
// register pressure, zero spill.

#define T_DIM   2048
#define W_WIN   64
#define BLOCK_T 256
#define STAGE   (BLOCK_T + W_WIN - 1)   // 319
#define CH      8
#define NCHUNK  (W_WIN / CH)            // 8

__global__ __launch_bounds__(BLOCK_T) void until_kernel(
    const float* __restrict__ phi,
    const float* __restrict__ psi,
    const int*  __restrict__ scale_p,
    float* __restrict__ out)
{
    // x = ep ch0, y = ep ch1, z = eq ch0, w = eq ch1
    __shared__ float4 s_d[STAGE];

    const int b   = blockIdx.y;
    const int t0  = blockIdx.x * BLOCK_T;
    const int tid = threadIdx.x;
    const float s  = (float)(*scale_p);
    const float ns = -s;

    const float2* __restrict__ phi2 = (const float2*)(phi + (size_t)b * T_DIM * 2);
    const float2* __restrict__ psi2 = (const float2*)(psi + (size_t)b * T_DIM * 2);

    // Stage: exp once per element. Past T: ep=0, eq=+inf.
    for (int i = tid; i < STAGE; i += BLOCK_T) {
        int t = t0 + i;
        float4 v;
        if (t < T_DIM) {
            float2 pv = phi2[t];
            float2 qv = psi2[t];
            v.x = __expf(ns * pv.x);
            v.y = __expf(ns * pv.y);
            v.z = __expf(ns * qv.x);
            v.w = __expf(ns * qv.y);
        } else {
            v.x = 0.f; v.y = 0.f;
            v.z = INFINITY; v.w = INFINITY;
        }
        s_d[i] = v;
    }
    __syncthreads();

    const float Es = __expf(ns);   // k==0 term: min_phi forced to 1.0

    float accA0 = 0.f, accA1 = 0.f;   // even-k accumulators
    float accB0 = 0.f, accB1 = 0.f;   // odd-k accumulators
    float sum0  = 0.f, sum1  = 0.f;   // running S_k

    const float4* __restrict__ sp = s_d + tid;

    // Double-buffered 8x8 chunked loop over k = 0..63.
    float4 buf[CH];
    #pragma unroll
    for (int j = 0; j < CH; ++j) buf[j] = sp[j];

    #pragma unroll
    for (int c = 0; c < NCHUNK; ++c) {
        float4 nxt[CH];
        if (c + 1 < NCHUNK) {
            #pragma unroll
            for (int j = 0; j < CH; ++j) nxt[j] = sp[(c + 1) * CH + j];
        }
        #pragma unroll
        for (int j = 0; j < CH; ++j) {
            const float4 v = buf[j];
            const bool k0 = (c == 0) && (j == 0);       // compile-time
            const float b0 = k0 ? Es : sum0;
            const float b1 = k0 ? Es : sum1;
            const float r0 = __builtin_amdgcn_rcpf(b0 + v.z);
            const float r1 = __builtin_amdgcn_rcpf(b1 + v.w);
            if (j & 1) { accB0 += r0; accB1 += r1; }
            else       { accA0 += r0; accA1 += r1; }
            sum0 += v.x;
            sum1 += v.y;
        }
        if (c + 1 < NCHUNK) {
            #pragma unroll
            for (int j = 0; j < CH; ++j) buf[j] = nxt[j];
        }
    }

    const int t = t0 + tid;
    float2* __restrict__ out2 = (float2*)(out + (size_t)b * T_DIM * 2);
    out2[t] = make_float2(__logf(accA0 + accB0) / s, __logf(accA1 + accB1) / s);
}

extern "C" void kernel_launch(void* const* d_in, const int* in_sizes, int n_in,
                              void* d_out, int out_size, void* d_ws, size_t ws_size,
                              hipStream_t stream) {
    const float* phi   = (const float*)d_in[0];
    const float* psi   = (const float*)d_in[1];
    const int*   scale = (const int*)d_in[2];
    float* out = (float*)d_out;

    const int B = in_sizes[0] / (T_DIM * 2);   // 64
    dim3 grid(T_DIM / BLOCK_T, B);             // (8, 64) = 512 blocks
    until_kernel<<<grid, dim3(BLOCK_T), 0, stream>>>(phi, psi, scale, out);
}